// Round 2
// baseline (1112.713 us; speedup 1.0000x reference)
//
#include <hip/hip_runtime.h>
#include <hip/hip_bf16.h>

#define D_MSA 384
#define NHEAD 12
#define DHID  32
#define BB    2
#define NN    256
#define LL    384

struct Smem {
  float tar[D_MSA];          // target sequence row (b, l, :)
  float q[D_MSA];            // q[h*32+d], already scaled
  float wf[NHEAD][D_MSA];    // w[h][c] = sum_d q[h,d]*Wk[h*32+d,c]
  float cb[NHEAD];           // q . bk per head
  float smax[NHEAD];
  float sinv[NHEAD];
  float attn[NHEAD][NN];     // logits, [h][n] for softmax over n
};

__global__ __launch_bounds__(512, 4)
void seqw_fused(const float* __restrict__ msa,
                const float* __restrict__ Wq,
                const float* __restrict__ bq,
                const float* __restrict__ Wk,
                const float* __restrict__ bk,
                float* __restrict__ out)
{
  __shared__ Smem sm;
  const int t    = threadIdx.x;
  const int lane = t & 63;
  const int wv   = t >> 6;        // 0..7
  const int rowi = lane >> 4;     // 0..3  : which row of the 4-row group
  const int seg  = lane & 15;     // 0..15 : 16 lanes cover one row's 384 floats
  const int bl   = blockIdx.x;
  const int b    = bl / LL;
  const int l    = bl - b * LL;
  const float scale = 0.17677669529663687f; // 1/sqrt(32)

  // ---- Phase A: tar_seq = msa[b, 0, l, :] -> LDS ----
  const float* targ = msa + ((size_t)(b * NN) * LL + l) * D_MSA;
  if (t < 96) ((float4*)sm.tar)[t] = ((const float4*)targ)[t];
  __syncthreads();

  // ---- Phase B: q[r] = scale * (tar . Wq[r,:] + bq[r]); 8 waves x 48 rows ----
  {
    float2 t2[3];
#pragma unroll
    for (int p = 0; p < 3; ++p) t2[p] = *(const float2*)&sm.tar[2 * lane + 128 * p];
    for (int j = 0; j < 48; ++j) {
      const int r = wv * 48 + j;
      const float* wr = Wq + (size_t)r * D_MSA;
      float s = 0.f;
#pragma unroll
      for (int p = 0; p < 3; ++p) {
        float2 w2 = *(const float2*)&wr[2 * lane + 128 * p];
        s = fmaf(t2[p].x, w2.x, s);
        s = fmaf(t2[p].y, w2.y, s);
      }
#pragma unroll
      for (int m = 32; m; m >>= 1) s += __shfl_xor(s, m);
      if (lane == 0) sm.q[r] = scale * (s + bq[r]);
    }
  }
  __syncthreads();

  // ---- Phase C: w[h][c] = q_h . Wk_h[:,c] (thread-per-column, coalesced) ----
  if (t < D_MSA) {
    const int c = t;
    float a[NHEAD];
#pragma unroll
    for (int h = 0; h < NHEAD; ++h) a[h] = 0.f;
    for (int d = 0; d < DHID; ++d) {
#pragma unroll
      for (int h = 0; h < NHEAD; ++h)
        a[h] = fmaf(sm.q[h * DHID + d], Wk[(size_t)(h * DHID + d) * D_MSA + c], a[h]);
    }
#pragma unroll
    for (int h = 0; h < NHEAD; ++h) sm.wf[h][c] = a[h];
  }
  if (t < NHEAD) {
    float s = 0.f;
#pragma unroll
    for (int d = 0; d < DHID; ++d) s = fmaf(sm.q[t * DHID + d], bk[t * DHID + d], s);
    sm.cb[t] = s;
  }
  __syncthreads();

  // ---- Main: wave wv owns rows [wv*32, wv*32+32); 16 lanes per row ----
  // Load instr: 16 lanes read contiguous 256B (coalesced). 12-head dots
  // accumulate per lane over its 24 c-values; reduce over the 16-lane group.
  const size_t rstride = (size_t)LL * D_MSA;
  const float* lanebase =
      msa + ((size_t)(b * NN + wv * 32 + rowi) * LL + l) * D_MSA + seg * 4;

#pragma unroll
  for (int bt = 0; bt < 2; ++bt) {
    float acc[4][NHEAD];
#pragma unroll
    for (int g = 0; g < 4; ++g)
#pragma unroll
      for (int h = 0; h < NHEAD; ++h) acc[g][h] = 0.f;

#pragma unroll
    for (int j = 0; j < 6; ++j) {
      float4 mv[4];
#pragma unroll
      for (int g = 0; g < 4; ++g)
        mv[g] = *(const float4*)(lanebase + (size_t)(bt * 16 + g * 4) * rstride + 64 * j);
#pragma unroll
      for (int h = 0; h < NHEAD; ++h) {
        float4 w4 = *(const float4*)&sm.wf[h][64 * j + 4 * seg];  // amortized over 16 rows
#pragma unroll
        for (int g = 0; g < 4; ++g) {
          acc[g][h] = fmaf(mv[g].x, w4.x, acc[g][h]);
          acc[g][h] = fmaf(mv[g].y, w4.y, acc[g][h]);
          acc[g][h] = fmaf(mv[g].z, w4.z, acc[g][h]);
          acc[g][h] = fmaf(mv[g].w, w4.w, acc[g][h]);
        }
      }
    }
    // reduce over the 16-lane seg group, write logits
#pragma unroll
    for (int g = 0; g < 4; ++g) {
      const int n = wv * 32 + bt * 16 + g * 4 + rowi;
#pragma unroll
      for (int h = 0; h < NHEAD; ++h) {
        float s = acc[g][h];
        s += __shfl_xor(s, 8);
        s += __shfl_xor(s, 4);
        s += __shfl_xor(s, 2);
        s += __shfl_xor(s, 1);
        if (seg == 0) sm.attn[h][n] = s + sm.cb[h];
      }
    }
  }
  __syncthreads();

  // ---- Softmax over n: waves 0..5 handle 2 heads each ----
  if (wv < 6) {
#pragma unroll
    for (int jh = 0; jh < 2; ++jh) {
      const int h = wv * 2 + jh;
      float v0 = sm.attn[h][lane];
      float v1 = sm.attn[h][lane + 64];
      float v2 = sm.attn[h][lane + 128];
      float v3 = sm.attn[h][lane + 192];
      float mx = fmaxf(fmaxf(v0, v1), fmaxf(v2, v3));
#pragma unroll
      for (int m = 32; m; m >>= 1) mx = fmaxf(mx, __shfl_xor(mx, m));
      float s = __expf(v0 - mx) + __expf(v1 - mx) + __expf(v2 - mx) + __expf(v3 - mx);
#pragma unroll
      for (int m = 32; m; m >>= 1) s += __shfl_xor(s, m);
      if (lane == 0) { sm.smax[h] = mx; sm.sinv[h] = 1.0f / s; }
    }
  }
  __syncthreads();

  // ---- Write out[b, n=t, l, :] for t < 256 (3 float4 stores) ----
  if (t < NN) {
    float o[NHEAD];
#pragma unroll
    for (int h = 0; h < NHEAD; ++h)
      o[h] = __expf(sm.attn[h][t] - sm.smax[h]) * sm.sinv[h];
    float* ob = out + ((size_t)(b * NN + t) * LL + l) * NHEAD;
    ((float4*)ob)[0] = make_float4(o[0], o[1], o[2],  o[3]);
    ((float4*)ob)[1] = make_float4(o[4], o[5], o[6],  o[7]);
    ((float4*)ob)[2] = make_float4(o[8], o[9], o[10], o[11]);
  }
}

extern "C" void kernel_launch(void* const* d_in, const int* in_sizes, int n_in,
                              void* d_out, int out_size, void* d_ws, size_t ws_size,
                              hipStream_t stream) {
  const float* msa = (const float*)d_in[0];
  const float* Wq  = (const float*)d_in[1];
  const float* bq  = (const float*)d_in[2];
  const float* Wk  = (const float*)d_in[3];
  const float* bk  = (const float*)d_in[4];
  float* out = (float*)d_out;

  dim3 grid(BB * LL);   // 768 blocks: one per (b, l)
  dim3 block(512);      // 8 waves; wave wv owns 32 n-rows, 16 lanes per row
  seqw_fused<<<grid, block, 0, stream>>>(msa, Wq, bq, Wk, bk, out);
}

// Round 3
// 216.790 us; speedup vs baseline: 5.1327x; 5.1327x over previous
//
#include <hip/hip_runtime.h>
#include <hip/hip_bf16.h>

#define D_MSA 384
#define NHEAD 12
#define DHID  32
#define BB    2
#define NN    256
#define LL    384

struct Smem {
  float tar[D_MSA];          // target sequence row (b, l, :)
  float q[D_MSA];            // q[h*32+d], already scaled
  float wf[NHEAD][D_MSA];    // w[h][c] = sum_d q[h,d]*Wk[h*32+d,c]
  float cb[NHEAD];           // q . bk per head
  float smax[NHEAD];
  float sinv[NHEAD];
  float attn[NHEAD][NN];     // logits, [h][n] for softmax over n
};

__global__ __launch_bounds__(512, 2)
void seqw_fused(const float* __restrict__ msa,
                const float* __restrict__ Wq,
                const float* __restrict__ bq,
                const float* __restrict__ Wk,
                const float* __restrict__ bk,
                float* __restrict__ out)
{
  __shared__ Smem sm;
  const int t    = threadIdx.x;
  const int lane = t & 63;
  const int wv   = t >> 6;        // 0..7
  const int rowi = lane >> 4;     // 0..3  : which row of the 4-row group
  const int seg  = lane & 15;     // 0..15 : 16 lanes cover one row's 384 floats
  const int bl   = blockIdx.x;
  const int b    = bl / LL;
  const int l    = bl - b * LL;
  const float scale = 0.17677669529663687f; // 1/sqrt(32)

  // ---- Phase A: tar_seq = msa[b, 0, l, :] -> LDS ----
  const float* targ = msa + ((size_t)(b * NN) * LL + l) * D_MSA;
  if (t < 96) ((float4*)sm.tar)[t] = ((const float4*)targ)[t];
  __syncthreads();

  // ---- Phase B: q[r] = scale * (tar . Wq[r,:] + bq[r]); 8 waves x 48 rows ----
  {
    float2 t2[3];
#pragma unroll
    for (int p = 0; p < 3; ++p) t2[p] = *(const float2*)&sm.tar[2 * lane + 128 * p];
#pragma unroll 1
    for (int j = 0; j < 48; ++j) {
      const int r = wv * 48 + j;
      const float* wr = Wq + (size_t)r * D_MSA;
      float s = 0.f;
#pragma unroll
      for (int p = 0; p < 3; ++p) {
        float2 w2 = *(const float2*)&wr[2 * lane + 128 * p];
        s = fmaf(t2[p].x, w2.x, s);
        s = fmaf(t2[p].y, w2.y, s);
      }
#pragma unroll
      for (int m = 32; m; m >>= 1) s += __shfl_xor(s, m);
      if (lane == 0) sm.q[r] = scale * (s + bq[r]);
    }
  }
  __syncthreads();

  // ---- Phase C: w[h][c] = q_h . Wk_h[:,c] (thread-per-column, coalesced) ----
  if (t < D_MSA) {
    const int c = t;
    float a[NHEAD];
#pragma unroll
    for (int h = 0; h < NHEAD; ++h) a[h] = 0.f;
#pragma unroll 1
    for (int d = 0; d < DHID; ++d) {
#pragma unroll
      for (int h = 0; h < NHEAD; ++h)
        a[h] = fmaf(sm.q[h * DHID + d], Wk[(size_t)(h * DHID + d) * D_MSA + c], a[h]);
    }
#pragma unroll
    for (int h = 0; h < NHEAD; ++h) sm.wf[h][c] = a[h];
  }
  if (t < NHEAD) {
    float s = 0.f;
#pragma unroll
    for (int d = 0; d < DHID; ++d) s = fmaf(sm.q[t * DHID + d], bk[t * DHID + d], s);
    sm.cb[t] = s;
  }
  __syncthreads();

  // ---- Main: wave wv owns rows [wv*32, wv*32+32); 16 lanes per row ----
  // Coalesced: per load instr a 16-lane group reads a contiguous 256B chunk.
  // Software-pipelined pairs of j-chunks; acc[4][12] + 2x4 float4 bufs live.
  const size_t rstride = (size_t)LL * D_MSA;
  const float* lanebase =
      msa + ((size_t)(b * NN + wv * 32 + rowi) * LL + l) * D_MSA + seg * 4;

#define LOADQ(buf, bt, j)                                                       \
  {                                                                             \
    _Pragma("unroll")                                                           \
    for (int g = 0; g < 4; ++g)                                                 \
      buf[g] = *(const float4*)(lanebase +                                      \
                 (size_t)((bt) * 16 + g * 4) * rstride + 64 * (j));             \
  }

#define COMPQ(buf, j)                                                           \
  {                                                                             \
    _Pragma("unroll")                                                           \
    for (int h = 0; h < NHEAD; ++h) {                                           \
      float4 w4 = *(const float4*)&sm.wf[h][64 * (j) + 4 * seg];                \
      _Pragma("unroll")                                                         \
      for (int g = 0; g < 4; ++g) {                                             \
        acc[g][h] = fmaf(buf[g].x, w4.x, acc[g][h]);                            \
        acc[g][h] = fmaf(buf[g].y, w4.y, acc[g][h]);                            \
        acc[g][h] = fmaf(buf[g].z, w4.z, acc[g][h]);                            \
        acc[g][h] = fmaf(buf[g].w, w4.w, acc[g][h]);                            \
      }                                                                         \
    }                                                                           \
  }

#pragma unroll 1
  for (int bt = 0; bt < 2; ++bt) {
    float acc[4][NHEAD];
#pragma unroll
    for (int g = 0; g < 4; ++g)
#pragma unroll
      for (int h = 0; h < NHEAD; ++h) acc[g][h] = 0.f;

    float4 bufA[4], bufB[4];
    LOADQ(bufA, bt, 0)
#pragma unroll 1
    for (int jj = 0; jj < 3; ++jj) {
      const int j0 = 2 * jj, j1 = 2 * jj + 1;
      LOADQ(bufB, bt, j1)
      COMPQ(bufA, j0)
      if (jj < 2) LOADQ(bufA, bt, j0 + 2)
      COMPQ(bufB, j1)
    }

    // reduce over the 16-lane seg group, write logits
#pragma unroll
    for (int g = 0; g < 4; ++g) {
      const int n = wv * 32 + bt * 16 + g * 4 + rowi;
#pragma unroll
      for (int h = 0; h < NHEAD; ++h) {
        float s = acc[g][h];
        s += __shfl_xor(s, 8);
        s += __shfl_xor(s, 4);
        s += __shfl_xor(s, 2);
        s += __shfl_xor(s, 1);
        if (seg == 0) sm.attn[h][n] = s + sm.cb[h];
      }
    }
  }
  __syncthreads();

  // ---- Softmax over n: waves 0..5 handle 2 heads each ----
  if (wv < 6) {
#pragma unroll
    for (int jh = 0; jh < 2; ++jh) {
      const int h = wv * 2 + jh;
      float v0 = sm.attn[h][lane];
      float v1 = sm.attn[h][lane + 64];
      float v2 = sm.attn[h][lane + 128];
      float v3 = sm.attn[h][lane + 192];
      float mx = fmaxf(fmaxf(v0, v1), fmaxf(v2, v3));
#pragma unroll
      for (int m = 32; m; m >>= 1) mx = fmaxf(mx, __shfl_xor(mx, m));
      float s = __expf(v0 - mx) + __expf(v1 - mx) + __expf(v2 - mx) + __expf(v3 - mx);
#pragma unroll
      for (int m = 32; m; m >>= 1) s += __shfl_xor(s, m);
      if (lane == 0) { sm.smax[h] = mx; sm.sinv[h] = 1.0f / s; }
    }
  }
  __syncthreads();

  // ---- Write out[b, n=t, l, :] for t < 256 (3 float4 stores) ----
  if (t < NN) {
    float o[NHEAD];
#pragma unroll
    for (int h = 0; h < NHEAD; ++h)
      o[h] = __expf(sm.attn[h][t] - sm.smax[h]) * sm.sinv[h];
    float* ob = out + ((size_t)(b * NN + t) * LL + l) * NHEAD;
    ((float4*)ob)[0] = make_float4(o[0], o[1], o[2],  o[3]);
    ((float4*)ob)[1] = make_float4(o[4], o[5], o[6],  o[7]);
    ((float4*)ob)[2] = make_float4(o[8], o[9], o[10], o[11]);
  }
}

extern "C" void kernel_launch(void* const* d_in, const int* in_sizes, int n_in,
                              void* d_out, int out_size, void* d_ws, size_t ws_size,
                              hipStream_t stream) {
  const float* msa = (const float*)d_in[0];
  const float* Wq  = (const float*)d_in[1];
  const float* bq  = (const float*)d_in[2];
  const float* Wk  = (const float*)d_in[3];
  const float* bk  = (const float*)d_in[4];
  float* out = (float*)d_out;

  dim3 grid(BB * LL);   // 768 blocks: one per (b, l)
  dim3 block(512);      // 8 waves; wave wv owns 32 n-rows, 16 lanes per row
  seqw_fused<<<grid, block, 0, stream>>>(msa, Wq, bq, Wk, bk, out);
}

// Round 4
// 172.248 us; speedup vs baseline: 6.4600x; 1.2586x over previous
//
#include <hip/hip_runtime.h>
#include <hip/hip_bf16.h>

#define D_MSA 384
#define NHEAD 12
#define DHID  32
#define BB    2
#define NN    256
#define LL    384
#define NBL   (BB * LL)          // 768 (b,l) pairs
#define WFROW (NHEAD * D_MSA)    // 4608

// ---- workspace layout (in floats) ----
#define WF_OFF 0
#define WF_SZ  ((size_t)NBL * WFROW)     // 3,538,944
#define Q_OFF  (WF_OFF + WF_SZ)
#define Q_SZ   ((size_t)NBL * D_MSA)     // 294,912
#define CB_OFF (Q_OFF + Q_SZ)
#define CB_SZ  ((size_t)NBL * NHEAD)     // 9,216
#define WS_FLOATS (CB_OFF + CB_SZ)
#define WS_BYTES  (WS_FLOATS * 4)

// =====================================================================
// A1: q[bl][c] = scale * (tar[bl] . Wq[c,:] + bq[c]);  cb[bl][h] = q_h . bk_h
// grid 96 blocks x 8 bl-rows, 256 threads. Wq traffic: 96 x 576KB = 55 MB.
// =====================================================================
__global__ __launch_bounds__(256)
void seqw_a1(const float* __restrict__ msa, const float* __restrict__ Wq,
             const float* __restrict__ bq, const float* __restrict__ bk,
             float* __restrict__ q_ws, float* __restrict__ cb_ws)
{
  __shared__ float tar[8][D_MSA];
  __shared__ float qs[8][D_MSA];
  const int t   = threadIdx.x;
  const int bl0 = blockIdx.x * 8;
  const int b   = bl0 / LL, l0 = bl0 % LL;   // 8-row groups never straddle b
  const float scale = 0.17677669529663687f;  // 1/sqrt(32)

  // tar rows are contiguous: msa[b][0][l0..l0+7][:]
  const float* base = msa + ((size_t)b * NN * LL + l0) * D_MSA;
  for (int i = t; i < 8 * D_MSA / 4; i += 256)
    ((float4*)tar)[i] = ((const float4*)base)[i];
  __syncthreads();

#pragma unroll 1
  for (int pass = 0; pass < 2; ++pass) {
    const int c = pass * 256 + t;
    if (c < D_MSA) {
      float acc[8];
#pragma unroll
      for (int r = 0; r < 8; ++r) acc[r] = 0.f;
      const float* wqr = Wq + (size_t)c * D_MSA;
#pragma unroll 2
      for (int k = 0; k < D_MSA; k += 4) {
        float4 w4 = *(const float4*)(wqr + k);
#pragma unroll
        for (int r = 0; r < 8; ++r) {
          float4 t4 = *(const float4*)&tar[r][k];
          acc[r] = fmaf(t4.x, w4.x, acc[r]);
          acc[r] = fmaf(t4.y, w4.y, acc[r]);
          acc[r] = fmaf(t4.z, w4.z, acc[r]);
          acc[r] = fmaf(t4.w, w4.w, acc[r]);
        }
      }
      const float bqc = bq[c];
#pragma unroll
      for (int r = 0; r < 8; ++r) {
        const float v = scale * (acc[r] + bqc);
        qs[r][c] = v;
        q_ws[(size_t)(bl0 + r) * D_MSA + c] = v;
      }
    }
  }
  __syncthreads();

  if (t < 8 * NHEAD) {
    const int r = t / NHEAD, h = t % NHEAD;
    float s = 0.f;
#pragma unroll
    for (int d = 0; d < DHID; ++d)
      s = fmaf(qs[r][h * DHID + d], bk[h * DHID + d], s);
    cb_ws[(size_t)(bl0 + r) * NHEAD + h] = s;
  }
}

// =====================================================================
// A2: wf[bl][h][c] = sum_d q[bl][h*32+d] * Wk[h*32+d][c]
// grid 12h x 48 tiles of 16 bl-rows, 256 threads. Wk traffic: 27 MB.
// =====================================================================
__global__ __launch_bounds__(256)
void seqw_a2(const float* __restrict__ Wk, const float* __restrict__ q_ws,
             float* __restrict__ wf_ws)
{
  __shared__ float qt[16][DHID];
  const int t   = threadIdx.x;
  const int h   = blockIdx.x % NHEAD;
  const int bl0 = (blockIdx.x / NHEAD) * 16;

  if (t < 128) {
    const int r = t >> 3, j = (t & 7) * 4;
    *(float4*)&qt[r][j] =
        *(const float4*)(q_ws + (size_t)(bl0 + r) * D_MSA + h * DHID + j);
  }
  __syncthreads();

#pragma unroll 1
  for (int pass = 0; pass < 2; ++pass) {
    const int c = pass * 256 + t;
    if (c < D_MSA) {
      float acc[16];
#pragma unroll
      for (int r = 0; r < 16; ++r) acc[r] = 0.f;
      const float* wkb = Wk + (size_t)(h * DHID) * D_MSA + c;
#pragma unroll 2
      for (int d = 0; d < DHID; d += 4) {
        const float w0 = wkb[(size_t)(d + 0) * D_MSA];
        const float w1 = wkb[(size_t)(d + 1) * D_MSA];
        const float w2 = wkb[(size_t)(d + 2) * D_MSA];
        const float w3 = wkb[(size_t)(d + 3) * D_MSA];
#pragma unroll
        for (int r = 0; r < 16; ++r) {
          float4 q4 = *(const float4*)&qt[r][d];
          acc[r] = fmaf(q4.x, w0, acc[r]);
          acc[r] = fmaf(q4.y, w1, acc[r]);
          acc[r] = fmaf(q4.z, w2, acc[r]);
          acc[r] = fmaf(q4.w, w3, acc[r]);
        }
      }
#pragma unroll
      for (int r = 0; r < 16; ++r)
        wf_ws[(size_t)(bl0 + r) * WFROW + h * D_MSA + c] = acc[r];
    }
  }
}

// =====================================================================
// B: stream msa, logits + softmax + write. One block per (b,l), 512 thr.
// Reads only its own 18KB wf slice (disjoint across blocks).
// =====================================================================
struct SmemB {
  float wf[NHEAD][D_MSA];
  float cb[NHEAD];
  float smax[NHEAD];
  float sinv[NHEAD];
  float attn[NHEAD][NN];
};

__global__ __launch_bounds__(512, 2)
void seqw_b(const float* __restrict__ msa, const float* __restrict__ wf_ws,
            const float* __restrict__ cb_ws, float* __restrict__ out)
{
  __shared__ SmemB sm;
  const int t    = threadIdx.x;
  const int lane = t & 63;
  const int wv   = t >> 6;        // 0..7
  const int rowi = lane >> 4;     // 0..3
  const int seg  = lane & 15;     // 0..15
  const int bl   = blockIdx.x;
  const int b    = bl / LL;
  const int l    = bl - b * LL;

  // load wf slice (1152 float4, coalesced) + cb
  {
    const float4* src = (const float4*)(wf_ws + (size_t)bl * WFROW);
    for (int i = t; i < WFROW / 4; i += 512) ((float4*)sm.wf)[i] = src[i];
    if (t < NHEAD) sm.cb[t] = cb_ws[(size_t)bl * NHEAD + t];
  }
  __syncthreads();

  const size_t rstride = (size_t)LL * D_MSA;
  const float* lanebase =
      msa + ((size_t)(b * NN + wv * 32 + rowi) * LL + l) * D_MSA + seg * 4;

#define LOADQ(buf, bt, j)                                                       \
  {                                                                             \
    _Pragma("unroll")                                                           \
    for (int g = 0; g < 4; ++g)                                                 \
      buf[g] = *(const float4*)(lanebase +                                      \
                 (size_t)((bt) * 16 + g * 4) * rstride + 64 * (j));             \
  }

#define COMPQ(buf, j)                                                           \
  {                                                                             \
    _Pragma("unroll")                                                           \
    for (int h = 0; h < NHEAD; ++h) {                                           \
      float4 w4 = *(const float4*)&sm.wf[h][64 * (j) + 4 * seg];                \
      _Pragma("unroll")                                                         \
      for (int g = 0; g < 4; ++g) {                                             \
        acc[g][h] = fmaf(buf[g].x, w4.x, acc[g][h]);                            \
        acc[g][h] = fmaf(buf[g].y, w4.y, acc[g][h]);                            \
        acc[g][h] = fmaf(buf[g].z, w4.z, acc[g][h]);                            \
        acc[g][h] = fmaf(buf[g].w, w4.w, acc[g][h]);                            \
      }                                                                         \
    }                                                                           \
  }

#pragma unroll 1
  for (int bt = 0; bt < 2; ++bt) {
    float acc[4][NHEAD];
#pragma unroll
    for (int g = 0; g < 4; ++g)
#pragma unroll
      for (int h = 0; h < NHEAD; ++h) acc[g][h] = 0.f;

    float4 bufA[4], bufB[4];
    LOADQ(bufA, bt, 0)
#pragma unroll 1
    for (int jj = 0; jj < 3; ++jj) {
      const int j0 = 2 * jj, j1 = 2 * jj + 1;
      LOADQ(bufB, bt, j1)
      COMPQ(bufA, j0)
      if (jj < 2) LOADQ(bufA, bt, j0 + 2)
      COMPQ(bufB, j1)
    }

#pragma unroll
    for (int g = 0; g < 4; ++g) {
      const int n = wv * 32 + bt * 16 + g * 4 + rowi;
#pragma unroll
      for (int h = 0; h < NHEAD; ++h) {
        float s = acc[g][h];
        s += __shfl_xor(s, 8);
        s += __shfl_xor(s, 4);
        s += __shfl_xor(s, 2);
        s += __shfl_xor(s, 1);
        if (seg == 0) sm.attn[h][n] = s + sm.cb[h];
      }
    }
  }
  __syncthreads();

  if (wv < 6) {
#pragma unroll
    for (int jh = 0; jh < 2; ++jh) {
      const int h = wv * 2 + jh;
      float v0 = sm.attn[h][lane];
      float v1 = sm.attn[h][lane + 64];
      float v2 = sm.attn[h][lane + 128];
      float v3 = sm.attn[h][lane + 192];
      float mx = fmaxf(fmaxf(v0, v1), fmaxf(v2, v3));
#pragma unroll
      for (int m = 32; m; m >>= 1) mx = fmaxf(mx, __shfl_xor(mx, m));
      float s = __expf(v0 - mx) + __expf(v1 - mx) + __expf(v2 - mx) + __expf(v3 - mx);
#pragma unroll
      for (int m = 32; m; m >>= 1) s += __shfl_xor(s, m);
      if (lane == 0) { sm.smax[h] = mx; sm.sinv[h] = 1.0f / s; }
    }
  }
  __syncthreads();

  if (t < NN) {
    float o[NHEAD];
#pragma unroll
    for (int h = 0; h < NHEAD; ++h)
      o[h] = __expf(sm.attn[h][t] - sm.smax[h]) * sm.sinv[h];
    float* ob = out + ((size_t)(b * NN + t) * LL + l) * NHEAD;
    ((float4*)ob)[0] = make_float4(o[0], o[1], o[2],  o[3]);
    ((float4*)ob)[1] = make_float4(o[4], o[5], o[6],  o[7]);
    ((float4*)ob)[2] = make_float4(o[8], o[9], o[10], o[11]);
  }
}

// =====================================================================
// Fallback: round-3 fused single kernel (used only if ws is too small)
// =====================================================================
struct SmemF {
  float tar[D_MSA];
  float q[D_MSA];
  float wf[NHEAD][D_MSA];
  float cb[NHEAD];
  float smax[NHEAD];
  float sinv[NHEAD];
  float attn[NHEAD][NN];
};

__global__ __launch_bounds__(512, 2)
void seqw_fused_fb(const float* __restrict__ msa, const float* __restrict__ Wq,
                   const float* __restrict__ bq, const float* __restrict__ Wk,
                   const float* __restrict__ bk, float* __restrict__ out)
{
  __shared__ SmemF sm;
  const int t    = threadIdx.x;
  const int lane = t & 63;
  const int wv   = t >> 6;
  const int rowi = lane >> 4;
  const int seg  = lane & 15;
  const int bl   = blockIdx.x;
  const int b    = bl / LL;
  const int l    = bl - b * LL;
  const float scale = 0.17677669529663687f;

  const float* targ = msa + ((size_t)(b * NN) * LL + l) * D_MSA;
  if (t < 96) ((float4*)sm.tar)[t] = ((const float4*)targ)[t];
  __syncthreads();

  {
    float2 t2[3];
#pragma unroll
    for (int p = 0; p < 3; ++p) t2[p] = *(const float2*)&sm.tar[2 * lane + 128 * p];
#pragma unroll 1
    for (int j = 0; j < 48; ++j) {
      const int r = wv * 48 + j;
      const float* wr = Wq + (size_t)r * D_MSA;
      float s = 0.f;
#pragma unroll
      for (int p = 0; p < 3; ++p) {
        float2 w2 = *(const float2*)&wr[2 * lane + 128 * p];
        s = fmaf(t2[p].x, w2.x, s);
        s = fmaf(t2[p].y, w2.y, s);
      }
#pragma unroll
      for (int m = 32; m; m >>= 1) s += __shfl_xor(s, m);
      if (lane == 0) sm.q[r] = scale * (s + bq[r]);
    }
  }
  __syncthreads();

  if (t < D_MSA) {
    const int c = t;
    float a[NHEAD];
#pragma unroll
    for (int h = 0; h < NHEAD; ++h) a[h] = 0.f;
#pragma unroll 1
    for (int d = 0; d < DHID; ++d) {
#pragma unroll
      for (int h = 0; h < NHEAD; ++h)
        a[h] = fmaf(sm.q[h * DHID + d], Wk[(size_t)(h * DHID + d) * D_MSA + c], a[h]);
    }
#pragma unroll
    for (int h = 0; h < NHEAD; ++h) sm.wf[h][c] = a[h];
  }
  if (t < NHEAD) {
    float s = 0.f;
#pragma unroll
    for (int d = 0; d < DHID; ++d) s = fmaf(sm.q[t * DHID + d], bk[t * DHID + d], s);
    sm.cb[t] = s;
  }
  __syncthreads();

  const size_t rstride = (size_t)LL * D_MSA;
  const float* lanebase =
      msa + ((size_t)(b * NN + wv * 32 + rowi) * LL + l) * D_MSA + seg * 4;

#define LOADQF(buf, bt, j)                                                      \
  {                                                                             \
    _Pragma("unroll")                                                           \
    for (int g = 0; g < 4; ++g)                                                 \
      buf[g] = *(const float4*)(lanebase +                                      \
                 (size_t)((bt) * 16 + g * 4) * rstride + 64 * (j));             \
  }
#define COMPQF(buf, j)                                                          \
  {                                                                             \
    _Pragma("unroll")                                                           \
    for (int h = 0; h < NHEAD; ++h) {                                           \
      float4 w4 = *(const float4*)&sm.wf[h][64 * (j) + 4 * seg];                \
      _Pragma("unroll")                                                         \
      for (int g = 0; g < 4; ++g) {                                             \
        acc[g][h] = fmaf(buf[g].x, w4.x, acc[g][h]);                            \
        acc[g][h] = fmaf(buf[g].y, w4.y, acc[g][h]);                            \
        acc[g][h] = fmaf(buf[g].z, w4.z, acc[g][h]);                            \
        acc[g][h] = fmaf(buf[g].w, w4.w, acc[g][h]);                            \
      }                                                                         \
    }                                                                           \
  }

#pragma unroll 1
  for (int bt = 0; bt < 2; ++bt) {
    float acc[4][NHEAD];
#pragma unroll
    for (int g = 0; g < 4; ++g)
#pragma unroll
      for (int h = 0; h < NHEAD; ++h) acc[g][h] = 0.f;
    float4 bufA[4], bufB[4];
    LOADQF(bufA, bt, 0)
#pragma unroll 1
    for (int jj = 0; jj < 3; ++jj) {
      const int j0 = 2 * jj, j1 = 2 * jj + 1;
      LOADQF(bufB, bt, j1)
      COMPQF(bufA, j0)
      if (jj < 2) LOADQF(bufA, bt, j0 + 2)
      COMPQF(bufB, j1)
    }
#pragma unroll
    for (int g = 0; g < 4; ++g) {
      const int n = wv * 32 + bt * 16 + g * 4 + rowi;
#pragma unroll
      for (int h = 0; h < NHEAD; ++h) {
        float s = acc[g][h];
        s += __shfl_xor(s, 8);
        s += __shfl_xor(s, 4);
        s += __shfl_xor(s, 2);
        s += __shfl_xor(s, 1);
        if (seg == 0) sm.attn[h][n] = s + sm.cb[h];
      }
    }
  }
  __syncthreads();

  if (wv < 6) {
#pragma unroll
    for (int jh = 0; jh < 2; ++jh) {
      const int h = wv * 2 + jh;
      float v0 = sm.attn[h][lane];
      float v1 = sm.attn[h][lane + 64];
      float v2 = sm.attn[h][lane + 128];
      float v3 = sm.attn[h][lane + 192];
      float mx = fmaxf(fmaxf(v0, v1), fmaxf(v2, v3));
#pragma unroll
      for (int m = 32; m; m >>= 1) mx = fmaxf(mx, __shfl_xor(mx, m));
      float s = __expf(v0 - mx) + __expf(v1 - mx) + __expf(v2 - mx) + __expf(v3 - mx);
#pragma unroll
      for (int m = 32; m; m >>= 1) s += __shfl_xor(s, m);
      if (lane == 0) { sm.smax[h] = mx; sm.sinv[h] = 1.0f / s; }
    }
  }
  __syncthreads();

  if (t < NN) {
    float o[NHEAD];
#pragma unroll
    for (int h = 0; h < NHEAD; ++h)
      o[h] = __expf(sm.attn[h][t] - sm.smax[h]) * sm.sinv[h];
    float* ob = out + ((size_t)(b * NN + t) * LL + l) * NHEAD;
    ((float4*)ob)[0] = make_float4(o[0], o[1], o[2],  o[3]);
    ((float4*)ob)[1] = make_float4(o[4], o[5], o[6],  o[7]);
    ((float4*)ob)[2] = make_float4(o[8], o[9], o[10], o[11]);
  }
}

extern "C" void kernel_launch(void* const* d_in, const int* in_sizes, int n_in,
                              void* d_out, int out_size, void* d_ws, size_t ws_size,
                              hipStream_t stream) {
  const float* msa = (const float*)d_in[0];
  const float* Wq  = (const float*)d_in[1];
  const float* bq  = (const float*)d_in[2];
  const float* Wk  = (const float*)d_in[3];
  const float* bk  = (const float*)d_in[4];
  float* out = (float*)d_out;

  if (ws_size >= WS_BYTES) {
    float* ws    = (float*)d_ws;
    float* wf_ws = ws + WF_OFF;
    float* q_ws  = ws + Q_OFF;
    float* cb_ws = ws + CB_OFF;
    seqw_a1<<<dim3(NBL / 8), dim3(256), 0, stream>>>(msa, Wq, bq, bk, q_ws, cb_ws);
    seqw_a2<<<dim3(NHEAD * (NBL / 16)), dim3(256), 0, stream>>>(Wk, q_ws, wf_ws);
    seqw_b<<<dim3(NBL), dim3(512), 0, stream>>>(msa, wf_ws, cb_ws, out);
  } else {
    seqw_fused_fb<<<dim3(NBL), dim3(512), 0, stream>>>(msa, Wq, bq, Wk, bk, out);
  }
}